// Round 4
// baseline (975.962 us; speedup 1.0000x reference)
//
#include <hip/hip_runtime.h>
#include <hip/hip_bf16.h>
#include <math.h>

#define Ntok 8192
#define Dm   1024
#define Hm   2048
#define NE   8

typedef __hip_bfloat16 bf16;
typedef __attribute__((ext_vector_type(8))) short short8;
typedef __attribute__((ext_vector_type(4))) float f32x4;

static __device__ __forceinline__ float b2f(bf16 v){ return __bfloat162float(v); }
static __device__ __forceinline__ bf16  f2b(float v){ return __float2bfloat16(v); }

// async global->LDS, 16B per lane; LDS dest wave-uniform base (lane i -> base + i*16)
static __device__ __forceinline__ void gl2lds16(const bf16* g, bf16* l) {
    __builtin_amdgcn_global_load_lds(
        (const __attribute__((address_space(1))) unsigned*)(const void*)g,
        (__attribute__((address_space(3))) unsigned*)(void*)l, 16, 0, 0);
}

// ---------------- dtype detect ----------------
__global__ void detect_kernel(const unsigned* __restrict__ xw, int* dtf)
{
    unsigned w = xw[threadIdx.x];
    int ex = (w >> 23) & 0xff;
    unsigned long long m = __ballot(ex < 200);
    if (threadIdx.x == 0) *dtf = (__popcll(m) > 32) ? 1 : 0;
}

// ---------------- gate: softmax + top-2 routing, fused x->bf16 conversion ----------------
__global__ void gate_kernel(const void* __restrict__ xv, const void* __restrict__ wgv,
                            const int* __restrict__ dtf,
                            int* cnt, float* Psum, float* wts, int* idx_buf,
                            bf16* __restrict__ xb)
{
    int fp32 = *dtf;
    int lane = threadIdx.x & 63;
    int wv   = threadIdx.x >> 6;
    int n    = blockIdx.x * 4 + wv;

    float acc[NE];
    #pragma unroll
    for (int e = 0; e < NE; e++) acc[e] = 0.f;

    if (fp32) {
        const float* xr = (const float*)xv + (size_t)n * Dm;
        const float* Wg = (const float*)wgv;
        #pragma unroll
        for (int i = 0; i < 4; i++) {
            int o = i*256 + lane*4;
            float4 xv4 = *(const float4*)(xr + o);
            bf16 t4[4] = { f2b(xv4.x), f2b(xv4.y), f2b(xv4.z), f2b(xv4.w) };
            *(uint2*)(xb + (size_t)n * Dm + o) = *(uint2*)t4;
            #pragma unroll
            for (int e = 0; e < NE; e++) {
                float4 w4 = *(const float4*)(Wg + e*Dm + o);
                acc[e] += xv4.x*w4.x + xv4.y*w4.y + xv4.z*w4.z + xv4.w*w4.w;
            }
        }
    } else {
        const bf16* xr = (const bf16*)xv + (size_t)n * Dm;
        const bf16* Wg = (const bf16*)wgv;
        #pragma unroll
        for (int i = 0; i < 4; i++) {
            int o = i*256 + lane*4;
            bf16 x4[4]; *(uint2*)x4 = *(const uint2*)(xr + o);
            *(uint2*)(xb + (size_t)n * Dm + o) = *(uint2*)x4;
            #pragma unroll
            for (int e = 0; e < NE; e++) {
                bf16 w4[4]; *(uint2*)w4 = *(const uint2*)(Wg + e*Dm + o);
                acc[e] += b2f(x4[0])*b2f(w4[0]) + b2f(x4[1])*b2f(w4[1])
                        + b2f(x4[2])*b2f(w4[2]) + b2f(x4[3])*b2f(w4[3]);
            }
        }
    }
    #pragma unroll
    for (int e = 0; e < NE; e++) {
        float v = acc[e];
        #pragma unroll
        for (int off = 32; off > 0; off >>= 1) v += __shfl_xor(v, off);
        acc[e] = v;
    }
    float mx = acc[0];
    #pragma unroll
    for (int e = 1; e < NE; e++) mx = fmaxf(mx, acc[e]);
    float p[NE]; float s = 0.f;
    #pragma unroll
    for (int e = 0; e < NE; e++) { p[e] = expf(acc[e] - mx); s += p[e]; }
    float inv = 1.f / s;
    #pragma unroll
    for (int e = 0; e < NE; e++) p[e] *= inv;
    int e0 = 0;
    #pragma unroll
    for (int e = 1; e < NE; e++) if (p[e] > p[e0]) e0 = e;
    int e1 = (e0 == 0) ? 1 : 0;
    #pragma unroll
    for (int e = 0; e < NE; e++) if (e != e0 && p[e] > p[e1]) e1 = e;

    if (lane < NE) atomicAdd(Psum + lane, p[lane]);
    if (lane == 0) {
        int p0 = atomicAdd(cnt + e0, 1);
        idx_buf[e0*Ntok + p0] = n;              // k=0
        int p1 = atomicAdd(cnt + e1, 1);
        idx_buf[e1*Ntok + p1] = n | 0x10000;    // k=1 flag in bit 16
        wts[2*n]   = p[e0];
        wts[2*n+1] = p[e1];
    }
}

// ---------------- aux loss + per-expert dense-slot offsets ----------------
__global__ void aux_kernel(const int* __restrict__ cnt, const float* __restrict__ Psum,
                           const int* __restrict__ dtf, int* __restrict__ offs,
                           void* __restrict__ out)
{
    if (threadIdx.x == 0) {
        float s = 0.f; int a = 0;
        for (int e = 0; e < NE; e++) {
            offs[e] = a; a += cnt[e];
            s += (float)cnt[e] * Psum[e];
        }
        float aux = 0.08f * s / (16384.f * 8192.f);
        if (*dtf) ((float*)out)[(size_t)Ntok * Dm] = aux;
        else      ((bf16*)out)[(size_t)Ntok * Dm] = f2b(aux);
    }
}

// ---------------- transpose (two sources, same shape): src[R][C] -> dst[C][R] bf16 ----------------
__global__ void transpose2_kernel(const void* __restrict__ sA, const void* __restrict__ sB,
                                  bf16* __restrict__ dA, bf16* __restrict__ dB,
                                  int R, int C, const int* __restrict__ dtf)
{
    __shared__ bf16 t[64][68];
    int mat = blockIdx.z >> 3, e = blockIdx.z & 7;
    const void* src = mat ? sB : sA;
    bf16* dst = mat ? dB : dA;
    size_t base = (size_t)e * R * C;
    int c0 = blockIdx.x * 64, r0 = blockIdx.y * 64;
    int tid = threadIdx.x;
    int lr = tid >> 4;
    int lc = (tid & 15) * 4;

    if (*dtf) {
        const float* s = (const float*)src + base;
        #pragma unroll
        for (int i = 0; i < 4; i++) {
            float4 v = *(const float4*)(s + (size_t)(r0 + lr + 16*i) * C + c0 + lc);
            t[lr+16*i][lc+0] = f2b(v.x); t[lr+16*i][lc+1] = f2b(v.y);
            t[lr+16*i][lc+2] = f2b(v.z); t[lr+16*i][lc+3] = f2b(v.w);
        }
    } else {
        const bf16* s = (const bf16*)src + base;
        #pragma unroll
        for (int i = 0; i < 4; i++) {
            bf16 v[4];
            *(uint2*)v = *(const uint2*)(s + (size_t)(r0 + lr + 16*i) * C + c0 + lc);
            t[lr+16*i][lc+0] = v[0]; t[lr+16*i][lc+1] = v[1];
            t[lr+16*i][lc+2] = v[2]; t[lr+16*i][lc+3] = v[3];
        }
    }
    __syncthreads();
    int oc = tid >> 2;
    int os = tid & 3;
    bf16 ov[16];
    #pragma unroll
    for (int j = 0; j < 16; j++) ov[j] = t[os*16 + j][oc];
    bf16* dp = dst + base + (size_t)(c0 + oc) * R + r0 + os*16;
    *(uint4*)dp       = *(uint4*)ov;
    *(uint4*)(dp + 8) = *(uint4*)(ov + 8);
}

// ---------------- ffn1: 128x128 tile, h = silu(xg@W1+b1)*(xg@W3+b3) ----------------
__global__ __launch_bounds__(256) void ffn1_kernel(
    const bf16* __restrict__ xb, const bf16* __restrict__ w1t, const bf16* __restrict__ w3t,
    const void* __restrict__ b1v, const void* __restrict__ b3v, const int* __restrict__ dtf,
    const int* __restrict__ cnt, const int* __restrict__ offs,
    const int* __restrict__ idx_buf, bf16* __restrict__ hbuf)
{
    int e = blockIdx.z;
    int c = cnt[e];
    int m0 = blockIdx.y * 128;
    if (m0 >= c) return;
    int h0 = blockIdx.x * 128;
    int fp32 = *dtf;
    int slot0 = offs[e] + m0;

    __shared__ __align__(16) bf16 aL[128][32];
    __shared__ __align__(16) bf16 bL1[128][32];
    __shared__ __align__(16) bf16 bL3[128][32];
    __shared__ int tk[128];

    int tid = threadIdx.x;
    if (tid < 128) {
        int m = m0 + tid; if (m > c - 1) m = c - 1;
        tk[tid] = idx_buf[e*Ntok + m] & 0xffff;
    }
    __syncthreads();

    const bf16* w1e = w1t + (size_t)e * Hm * Dm;
    const bf16* w3e = w3t + (size_t)e * Hm * Dm;

    int lane = tid & 63, wv = tid >> 6;
    int wm = wv >> 1, wn = wv & 1;
    int mrow = lane & 15, kg = lane >> 4;

    // wave wv stages rows [32wv, 32wv+32) of each 128x32 tile; 2 gl2lds per tile
    int srow = 32*wv + (lane >> 2);
    int sseg = (lane & 3) * 8;
    const bf16* gA0 = xb + (size_t)tk[srow]      * Dm + sseg;
    const bf16* gA1 = xb + (size_t)tk[srow + 16] * Dm + sseg;
    const bf16* g1a = w1e + (size_t)(h0 + srow     ) * Dm + sseg;
    const bf16* g1b = w1e + (size_t)(h0 + srow + 16) * Dm + sseg;
    const bf16* g3a = w3e + (size_t)(h0 + srow     ) * Dm + sseg;
    const bf16* g3b = w3e + (size_t)(h0 + srow + 16) * Dm + sseg;
    bf16* lA0 = &aL [32*wv   ][0];
    bf16* lA1 = &aL [32*wv+16][0];
    bf16* l1a = &bL1[32*wv   ][0];
    bf16* l1b = &bL1[32*wv+16][0];
    bf16* l3a = &bL3[32*wv   ][0];
    bf16* l3b = &bL3[32*wv+16][0];

    f32x4 acc1[4][4], acc3[4][4];
    f32x4 z = {0.f, 0.f, 0.f, 0.f};
    #pragma unroll
    for (int ms = 0; ms < 4; ms++)
        #pragma unroll
        for (int ns = 0; ns < 4; ns++) { acc1[ms][ns] = z; acc3[ms][ns] = z; }

    for (int k0 = 0; k0 < Dm; k0 += 32) {
        gl2lds16(gA0, lA0); gl2lds16(gA1, lA1);
        gl2lds16(g1a, l1a); gl2lds16(g1b, l1b);
        gl2lds16(g3a, l3a); gl2lds16(g3b, l3b);
        gA0 += 32; gA1 += 32; g1a += 32; g1b += 32; g3a += 32; g3b += 32;
        __syncthreads();

        short8 af[4], b1f[4], b3f[4];
        #pragma unroll
        for (int ms = 0; ms < 4; ms++)
            af[ms] = *(const short8*)&aL[wm*64 + ms*16 + mrow][kg*8];
        #pragma unroll
        for (int ns = 0; ns < 4; ns++) {
            b1f[ns] = *(const short8*)&bL1[wn*64 + ns*16 + mrow][kg*8];
            b3f[ns] = *(const short8*)&bL3[wn*64 + ns*16 + mrow][kg*8];
        }
        #pragma unroll
        for (int ms = 0; ms < 4; ms++)
            #pragma unroll
            for (int ns = 0; ns < 4; ns++) {
                acc1[ms][ns] = __builtin_amdgcn_mfma_f32_16x16x32_bf16(af[ms], b1f[ns], acc1[ms][ns], 0, 0, 0);
                acc3[ms][ns] = __builtin_amdgcn_mfma_f32_16x16x32_bf16(af[ms], b3f[ns], acc3[ms][ns], 0, 0, 0);
            }
        __syncthreads();
    }

    #pragma unroll
    for (int ns = 0; ns < 4; ns++) {
        int col = h0 + wn*64 + ns*16 + mrow;
        float bb1 = fp32 ? ((const float*)b1v)[e*Hm + col] : b2f(((const bf16*)b1v)[e*Hm + col]);
        float bb3 = fp32 ? ((const float*)b3v)[e*Hm + col] : b2f(((const bf16*)b3v)[e*Hm + col]);
        #pragma unroll
        for (int ms = 0; ms < 4; ms++) {
            int rbase = wm*64 + ms*16 + kg*4;
            #pragma unroll
            for (int r = 0; r < 4; r++) {
                int rr = rbase + r;
                if (m0 + rr < c) {
                    float v1 = acc1[ms][ns][r] + bb1;
                    float v3 = acc3[ms][ns][r] + bb3;
                    float hv = (v1 / (1.f + expf(-v1))) * v3;
                    hbuf[(size_t)(slot0 + rr)*Hm + col] = f2b(hv);
                }
            }
        }
    }
}

// ---------------- ffn2: 128x128 tile, out_slot = (h @ W2 + b2) * w ----------------
__global__ __launch_bounds__(256) void ffn2_kernel(
    const bf16* __restrict__ hbuf, const bf16* __restrict__ w2t, const void* __restrict__ b2v,
    const int* __restrict__ dtf, const int* __restrict__ cnt, const int* __restrict__ offs,
    const int* __restrict__ idx_buf, const float* __restrict__ wts, bf16* __restrict__ outs)
{
    int e = blockIdx.z;
    int c = cnt[e];
    int m0 = blockIdx.y * 128;
    if (m0 >= c) return;
    int d0 = blockIdx.x * 128;
    int fp32 = *dtf;
    int slot0 = offs[e] + m0;

    __shared__ __align__(16) bf16 aL[128][32];
    __shared__ __align__(16) bf16 bL[128][32];
    __shared__ int rl[128];
    __shared__ float wL[128];

    int tid = threadIdx.x;
    if (tid < 128) {
        int m = m0 + tid; if (m > c - 1) m = c - 1;
        int v = idx_buf[e*Ntok + m];
        int slot = 2*(v & 0xffff) + (v >> 16);
        rl[tid] = slot;
        wL[tid] = wts[slot];
    }
    __syncthreads();

    const bf16* w2e = w2t + (size_t)e * Dm * Hm;

    int lane = tid & 63, wv = tid >> 6;
    int wm = wv >> 1, wn = wv & 1;
    int mrow = lane & 15, kg = lane >> 4;

    int srow = 32*wv + (lane >> 2);
    int sseg = (lane & 3) * 8;
    int ga0 = slot0 + srow;      if (ga0 > 2*Ntok - 1) ga0 = 2*Ntok - 1;
    int ga1 = slot0 + srow + 16; if (ga1 > 2*Ntok - 1) ga1 = 2*Ntok - 1;
    const bf16* gA0 = hbuf + (size_t)ga0 * Hm + sseg;
    const bf16* gA1 = hbuf + (size_t)ga1 * Hm + sseg;
    const bf16* g2a = w2e + (size_t)(d0 + srow     ) * Hm + sseg;
    const bf16* g2b = w2e + (size_t)(d0 + srow + 16) * Hm + sseg;
    bf16* lA0 = &aL[32*wv   ][0];
    bf16* lA1 = &aL[32*wv+16][0];
    bf16* l2a = &bL[32*wv   ][0];
    bf16* l2b = &bL[32*wv+16][0];

    f32x4 acc[4][4];
    f32x4 z = {0.f, 0.f, 0.f, 0.f};
    #pragma unroll
    for (int ms = 0; ms < 4; ms++)
        #pragma unroll
        for (int ns = 0; ns < 4; ns++) acc[ms][ns] = z;

    for (int k0 = 0; k0 < Hm; k0 += 32) {
        gl2lds16(gA0, lA0); gl2lds16(gA1, lA1);
        gl2lds16(g2a, l2a); gl2lds16(g2b, l2b);
        gA0 += 32; gA1 += 32; g2a += 32; g2b += 32;
        __syncthreads();

        short8 af[4], bfr[4];
        #pragma unroll
        for (int ms = 0; ms < 4; ms++)
            af[ms] = *(const short8*)&aL[wm*64 + ms*16 + mrow][kg*8];
        #pragma unroll
        for (int ns = 0; ns < 4; ns++)
            bfr[ns] = *(const short8*)&bL[wn*64 + ns*16 + mrow][kg*8];
        #pragma unroll
        for (int ms = 0; ms < 4; ms++)
            #pragma unroll
            for (int ns = 0; ns < 4; ns++)
                acc[ms][ns] = __builtin_amdgcn_mfma_f32_16x16x32_bf16(af[ms], bfr[ns], acc[ms][ns], 0, 0, 0);
        __syncthreads();
    }

    #pragma unroll
    for (int ns = 0; ns < 4; ns++) {
        int col = d0 + wn*64 + ns*16 + mrow;
        float bb2 = fp32 ? ((const float*)b2v)[e*Dm + col] : b2f(((const bf16*)b2v)[e*Dm + col]);
        #pragma unroll
        for (int ms = 0; ms < 4; ms++) {
            int rbase = wm*64 + ms*16 + kg*4;
            #pragma unroll
            for (int r = 0; r < 4; r++) {
                int rr = rbase + r;
                if (m0 + rr < c)
                    outs[(size_t)rl[rr]*Dm + col] = f2b((acc[ms][ns][r] + bb2) * wL[rr]);
            }
        }
    }
}

// ---------------- combine: y[n] = out[2n] + out[2n+1] (weights pre-applied) ----------------
__global__ void combine_kernel(const bf16* __restrict__ outs,
                               const int* __restrict__ dtf, void* __restrict__ yv)
{
    int gid = blockIdx.x * 256 + threadIdx.x;
    int n = gid >> 7;
    int j = (gid & 127) * 8;
    bf16 ra[8], rb[8];
    *(uint4*)ra = *(const uint4*)(outs + (size_t)(2*n)   * Dm + j);
    *(uint4*)rb = *(const uint4*)(outs + (size_t)(2*n+1) * Dm + j);
    float o[8];
    #pragma unroll
    for (int t = 0; t < 8; t++)
        o[t] = b2f(ra[t]) + b2f(rb[t]);
    if (*dtf) {
        float* y = (float*)yv + (size_t)n * Dm + j;
        *(float4*)y       = make_float4(o[0], o[1], o[2], o[3]);
        *(float4*)(y + 4) = make_float4(o[4], o[5], o[6], o[7]);
    } else {
        bf16 ro[8];
        #pragma unroll
        for (int t = 0; t < 8; t++) ro[t] = f2b(o[t]);
        *(uint4*)((bf16*)yv + (size_t)n * Dm + j) = *(uint4*)ro;
    }
}

extern "C" void kernel_launch(void* const* d_in, const int* in_sizes, int n_in,
                              void* d_out, int out_size, void* d_ws, size_t ws_size,
                              hipStream_t stream)
{
    (void)in_sizes; (void)n_in; (void)out_size; (void)ws_size;
    const void* x  = d_in[0];
    const void* Wg = d_in[1];
    const void* W1 = d_in[2];
    const void* b1 = d_in[3];
    const void* W2 = d_in[4];
    const void* b2 = d_in[5];
    const void* W3 = d_in[6];
    const void* b3 = d_in[7];

    char* ws = (char*)d_ws;
    int*   cnt  = (int*)ws;
    int*   dtf  = (int*)(ws + 64);
    float* Psum = (float*)(ws + 256);
    int*   offs = (int*)(ws + 512);
    float* wts  = (float*)(ws + 4096);            // 64 KB -> 69632
    int*   idx  = (int*)(ws + 69632);             // 256 KB -> 331776
    bf16*  xb   = (bf16*)(ws + 331776);           // 16 MiB -> 17108992
    bf16*  bufA = (bf16*)(ws + 17108992);         // 32 MiB (w1t, then w2t)
    bf16*  bufB = (bf16*)(ws + 50663424);         // 32 MiB (w3t, then outs)
    bf16*  hbuf = (bf16*)(ws + 84217856);         // 64 MiB -> ends 151326720 (~144.3 MiB)
    bf16*  outs = bufB;

    hipMemsetAsync(d_ws, 0, 4096, stream);
    detect_kernel<<<1, 64, 0, stream>>>((const unsigned*)x, dtf);
    gate_kernel<<<Ntok/4, 256, 0, stream>>>(x, Wg, dtf, cnt, Psum, wts, idx, xb);
    aux_kernel<<<1, 64, 0, stream>>>(cnt, Psum, dtf, offs, d_out);
    // W1,W3: [D][H] -> [H][D]
    transpose2_kernel<<<dim3(Hm/64, Dm/64, 16), 256, 0, stream>>>(W1, W3, bufA, bufB, Dm, Hm, dtf);
    ffn1_kernel<<<dim3(Hm/128, Ntok/128, NE), 256, 0, stream>>>(xb, bufA, bufB, b1, b3, dtf, cnt, offs, idx, hbuf);
    // W2: [H][D] -> [D][H]  (into bufA, w1t dead)
    transpose2_kernel<<<dim3(Dm/64, Hm/64, 8), 256, 0, stream>>>(W2, W2, bufA, bufA, Hm, Dm, dtf);
    ffn2_kernel<<<dim3(Dm/128, Ntok/128, NE), 256, 0, stream>>>(hbuf, bufA, b2, dtf, cnt, offs, idx, wts, outs);
    combine_kernel<<<(Ntok*Dm/8)/256, 256, 0, stream>>>(outs, dtf, d_out);
}